// Round 1
// baseline (550.684 us; speedup 1.0000x reference)
//
#include <hip/hip_runtime.h>

// CRF Viterbi decode, B=256, T=512, C=128.
// Outputs (flat float32, concatenated): viterbi [B,T], inputs copy [B,T,C],
// seq_len [B], transitions copy [C,C].

#define BB 256
#define TT 512
#define CC 128
#define NTHREADS 512
#define GROUPS 4            // cprev split across thread groups
#define JPER (CC / GROUPS)  // 32 cprev per thread

#define OFF_VIT 0
#define OFF_INP (BB * TT)                 // 131072
#define OFF_LEN (OFF_INP + BB * TT * CC)  // 16908288
#define OFF_TR (OFF_LEN + BB)             // 16908544

// LDS partition (dynamic, ~71 KB — above the 64KB static-LDS comfort zone,
// gfx950 allows up to 160KB per workgroup)
#define BP_BYTES ((TT - 1) * CC)             // 65408, 16B-aligned
#define SMEM_BYTES (BP_BYTES + CC * 4 /*state*/ + CC * 5 * 4 /*val*/ + CC * 5 * 4 /*idx*/ + 8 * 4 /*wsum*/ + 16)

__device__ __forceinline__ float readlane_f(float v, int lane) {
  return __int_as_float(__builtin_amdgcn_readlane(__float_as_int(v), lane));
}

__global__ __launch_bounds__(NTHREADS, 1) void crf_viterbi(
    const float* __restrict__ inputs, const unsigned char* __restrict__ mask_bytes,
    const float* __restrict__ trans, float* __restrict__ out) {
  extern __shared__ unsigned char smem[];
  unsigned char* bp_s = smem;                          // [T-1][C] u8 backpointers
  float* state_s = (float*)(smem + BP_BYTES);          // [C]
  float* val_s = state_s + CC;                         // [C][5] (stride-5: bank-conflict-free)
  int* idx_s = (int*)(val_s + CC * 5);                 // [C][5]
  int* wsum = idx_s + CC * 5;                          // [8]
  volatile int* sL = wsum + 8;

  const int b = blockIdx.x;
  const int tid = threadIdx.x;
  const int lane = tid & 63;
  const int ccur = tid & (CC - 1);
  const int g = tid >> 7;  // 0..3 (cprev group; uniform per wave)
  const int wave = tid >> 6;

  // --- mask element byte-width detection: int32 (byte1==0) vs bool/int8 ---
  const int w = (mask_bytes[1] == 0) ? 4 : 1;

  // --- sequence length L = popcount(mask[b,:]) (mask is a prefix mask) ---
  int mbit = (mask_bytes[(size_t)(b * TT + tid) * (size_t)w] != 0) ? 1 : 0;
  unsigned long long bal = __ballot(mbit);
  if (lane == 0) wsum[wave] = __popcll(bal);

  // --- preload transition fragment into registers: tr[j] = trans[(g*32+j)][ccur] ---
  float tr[JPER];
#pragma unroll
  for (int j = 0; j < JPER; ++j) tr[j] = trans[(g * JPER + j) * CC + ccur];

  const float* pin = inputs + (size_t)b * TT * CC;

  // --- init state = inputs[b, 0, :] ---
  if (tid < CC) state_s[tid] = pin[tid];
  __syncthreads();
  if (tid == 0) {
    int L = 0;
#pragma unroll
    for (int i = 0; i < 8; ++i) L += wsum[i];
    *sL = L;
  }
  __syncthreads();
  const int L = *sL;

  // --- forward DP: t = 1 .. L-1 (mask is prefix => exactly these steps valid) ---
  for (int t = 1; t < L; ++t) {
    // lanes 0..31 of each wave hold this group's 32 state values (2-way broadcast read: free)
    float sv = state_s[g * JPER + (lane & (JPER - 1))];
    float pot = 0.f;
    if (tid < CC) pot = pin[t * CC + ccur];  // prefetched; consumed after barrier

    float best = -INFINITY;
    int bidx = 0;
#pragma unroll
    for (int j = 0; j < JPER; ++j) {
      float v = readlane_f(sv, j) + tr[j];
      if (v > best) { best = v; bidx = j; }  // strict >: first-max (ascending cprev)
    }
    val_s[ccur * 5 + g] = best;
    idx_s[ccur * 5 + g] = g * JPER + bidx;
    __syncthreads();

    if (tid < CC) {
      float bv = val_s[ccur * 5 + 0];
      int bi = idx_s[ccur * 5 + 0];
#pragma unroll
      for (int gg = 1; gg < GROUPS; ++gg) {
        float v2 = val_s[ccur * 5 + gg];
        int i2 = idx_s[ccur * 5 + gg];
        if (v2 > bv) { bv = v2; bi = i2; }  // strict >: lower group (lower cprev) wins ties
      }
      state_s[ccur] = bv + pot;  // pot added after argmax (matches reference)
      bp_s[(t - 1) * CC + ccur] = (unsigned char)bi;
    }
    __syncthreads();
  }

  // --- epilogue: wave 0 = argmax + backtrack; waves 1..7 = bulk copies (overlapped) ---
  if (wave == 0) {
    // first-max argmax over 128 final-state entries
    float v1 = state_s[lane], v2 = state_s[lane + 64];
    float v;
    int idx;
    if (v2 > v1) { v = v2; idx = lane + 64; } else { v = v1; idx = lane; }
#pragma unroll
    for (int off = 32; off; off >>= 1) {
      float ov = __shfl_xor(v, off);
      int oi = __shfl_xor(idx, off);
      if (ov > v || (ov == v && oi < idx)) { v = ov; idx = oi; }
    }
    // tags for t >= L-1 all equal last_tag (identity backpointers past length)
    for (int t = L - 1 + lane; t < TT; t += 64) out[OFF_VIT + b * TT + t] = (float)idx;
    if (lane == 0) {
      int cur = idx;
      for (int tt = L - 2; tt >= 0; --tt) {
        cur = bp_s[tt * CC + cur];
        out[OFF_VIT + b * TT + tt] = (float)cur;
      }
      out[OFF_LEN + b] = (float)L;
    }
  } else {
    if (wave == 1) out[OFF_TR + b * 64 + lane] = trans[b * 64 + lane];  // 64 floats/block
    // copy this batch's input slice (256 KB) to d_out
    const float4* src = (const float4*)pin;
    float4* dst = (float4*)(out + OFF_INP + (size_t)b * TT * CC);
    for (int i = tid - 64; i < TT * CC / 4; i += NTHREADS - 64) dst[i] = src[i];
  }
}

extern "C" void kernel_launch(void* const* d_in, const int* in_sizes, int n_in,
                              void* d_out, int out_size, void* d_ws, size_t ws_size,
                              hipStream_t stream) {
  const float* inputs = (const float*)d_in[0];
  const unsigned char* mask = (const unsigned char*)d_in[1];
  const float* trans = (const float*)d_in[2];
  float* out = (float*)d_out;

  crf_viterbi<<<BB, NTHREADS, SMEM_BYTES, stream>>>(inputs, mask, trans, out);
}

// Round 2
// 501.878 us; speedup vs baseline: 1.0972x; 1.0972x over previous
//
#include <hip/hip_runtime.h>

// CRF Viterbi decode, B=256, T=512, C=128.
// Outputs (flat f32): viterbi [B,T], inputs copy [B,T,C], seq_len [B], trans copy [C,C].
//
// Structure: 1024 threads/block, 1 block per batch (256 blocks = 256 CUs).
// Thread (ccur = tid>>3, g = tid&7): 8 partials per tag live in 8 adjacent
// lanes -> in-wave DPP merge, ONE barrier per DP step.

#define BB 256
#define TT 512
#define CC 128
#define NTH 1024
#define GR 8    // groups (cluster of 8 lanes per tag)
#define JP 16   // cprev handled per thread
#define SPAD 20 // padded dword stride per group: g*20 mod 32 all-distinct -> conflict-free b128

#define OFF_VIT 0
#define OFF_INP (BB * TT)                 // 131072
#define OFF_LEN (OFF_INP + BB * TT * CC)  // 16908288
#define OFF_TR (OFF_LEN + BB)             // 16908544

#define BP_BYTES ((TT - 1) * CC)    // 65408, 16B aligned
#define STATE_FLOATS (2 * GR * SPAD)  // double-buffered padded state
#define SMEM_BYTES (BP_BYTES + STATE_FLOATS * 4 + 16 * 4 + 16)

template <int CTRL>
__device__ __forceinline__ void dpp_first_max(float& v, int& bi) {
  // pull partner lane's (val, idx); take it if strictly greater, or equal with
  // smaller global cprev index (reference jnp.argmax = first max)
  float ov = __int_as_float(__builtin_amdgcn_update_dpp(0, __float_as_int(v), CTRL, 0xF, 0xF, true));
  int oi = __builtin_amdgcn_update_dpp(0, bi, CTRL, 0xF, 0xF, true);
  bool take = (ov > v) || (ov == v && oi < bi);
  v = take ? ov : v;
  bi = take ? oi : bi;
}

#define CHAIN(VNAME, JIDX, BACC, IACC)              \
  {                                                 \
    float VNAME = sjv + tr[JIDX];                   \
    if (VNAME > BACC) { BACC = VNAME; IACC = JIDX; } \
  }

__global__ __launch_bounds__(NTH, 1) void crf_viterbi(
    const float* __restrict__ inputs, const unsigned char* __restrict__ mask_bytes,
    const float* __restrict__ trans, float* __restrict__ out) {
  extern __shared__ unsigned char smem[];
  unsigned char* bp_s = smem;                     // [T-1][C] u8 backpointers
  float* state_s = (float*)(smem + BP_BYTES);     // [2][GR*SPAD] padded state
  int* wsum = (int*)(state_s + STATE_FLOATS);     // [16]

  const int b = blockIdx.x;
  const int tid = threadIdx.x;
  const int lane = tid & 63;
  const int wave = tid >> 6;
  const int ccur = tid >> 3;  // 0..127 (8 lanes per tag)
  const int g = tid & 7;      // group within cluster

  // mask dtype detection: int32 (byte1 of elem0 == 0) vs bool/int8
  const int w4 = (mask_bytes[1] == 0) ? 4 : 1;
  if (tid < TT) {
    int mb = mask_bytes[(size_t)(b * TT + tid) * (size_t)w4] != 0;
    unsigned long long bal = __ballot(mb);
    if (lane == 0) wsum[wave] = __popcll(bal);
  }

  // transition fragment in registers: tr[j] = trans[g*16+j][ccur]
  float tr[JP];
#pragma unroll
  for (int j = 0; j < JP; ++j) tr[j] = trans[(g * JP + j) * CC + ccur];

  const float* pin = inputs + (size_t)b * TT * CC;

  // init state(t=0) into buffer 0 (padded layout)
  if (tid < CC) state_s[(tid >> 4) * SPAD + (tid & 15)] = pin[tid];
  __syncthreads();

  int L = 0;
#pragma unroll
  for (int i = 0; i < 8; ++i) L += wsum[i];  // L >= 256 by construction

  float pot = pin[CC + ccur];  // pot for t=1, prefetched
  int par = 0;

  for (int t = 1; t < L; ++t) {
    // this group's 16 prev-state values: 4x ds_read_b128, bank-conflict-free
    const float4* sp = (const float4*)(state_s + par * (GR * SPAD) + g * SPAD);
    float4 a0 = sp[0], a1 = sp[1], a2 = sp[2], a3 = sp[3];

    // prefetch next step's pot (hidden under this step's compute)
    int tn = (t + 1 < L) ? (t + 1) : t;
    float potN = pin[tn * CC + ccur];

    // phase 1: 16 cells, two independent accumulator chains (even/odd j)
    float b0 = a0.x + tr[0]; int i0 = 0;
    float b1 = a0.y + tr[1]; int i1 = 1;
    { float sjv = a0.z; CHAIN(v2, 2, b0, i0) }
    { float sjv = a0.w; CHAIN(v3, 3, b1, i1) }
    { float sjv = a1.x; CHAIN(v4, 4, b0, i0) }
    { float sjv = a1.y; CHAIN(v5, 5, b1, i1) }
    { float sjv = a1.z; CHAIN(v6, 6, b0, i0) }
    { float sjv = a1.w; CHAIN(v7, 7, b1, i1) }
    { float sjv = a2.x; CHAIN(v8, 8, b0, i0) }
    { float sjv = a2.y; CHAIN(v9, 9, b1, i1) }
    { float sjv = a2.z; CHAIN(vA, 10, b0, i0) }
    { float sjv = a2.w; CHAIN(vB, 11, b1, i1) }
    { float sjv = a3.x; CHAIN(vC, 12, b0, i0) }
    { float sjv = a3.y; CHAIN(vD, 13, b1, i1) }
    { float sjv = a3.z; CHAIN(vE, 14, b0, i0) }
    { float sjv = a3.w; CHAIN(vF, 15, b1, i1) }

    // merge chains (first-max: tie -> smaller j)
    bool t1 = (b1 > b0) || (b1 == b0 && i1 < i0);
    float v = t1 ? b1 : b0;
    int bi = (t1 ? i1 : i0) + g * JP;  // global cprev index

    // in-wave cluster reduce over the 8 groups (8 adjacent lanes)
    dpp_first_max<0xB1>(v, bi);   // quad_perm xor1
    dpp_first_max<0x4E>(v, bi);   // quad_perm xor2
    dpp_first_max<0x141>(v, bi);  // row_half_mirror (combine quad halves of 8)

    v += pot;  // reference adds pot AFTER max/argmax

    if (g == 0) {
      state_s[(par ^ 1) * (GR * SPAD) + (ccur >> 4) * SPAD + (ccur & 15)] = v;
      bp_s[(t - 1) * CC + ccur] = (unsigned char)bi;
    }
    pot = potN;
    __syncthreads();
    par ^= 1;
  }

  // --- epilogue: wave 0 = final argmax + backtrack; waves 1..15 = bulk copies ---
  if (wave == 0) {
    const float* fs = state_s + par * (GR * SPAD);
    float v1 = fs[(lane >> 4) * SPAD + (lane & 15)];
    int c2 = lane + 64;
    float v2 = fs[(c2 >> 4) * SPAD + (c2 & 15)];
    float v;
    int idx;
    if (v2 > v1) { v = v2; idx = c2; } else { v = v1; idx = lane; }
#pragma unroll
    for (int off = 32; off; off >>= 1) {
      float ov = __shfl_xor(v, off);
      int oi = __shfl_xor(idx, off);
      if (ov > v || (ov == v && oi < idx)) { v = ov; idx = oi; }
    }
    // tags for t >= L-1 all equal last_tag (identity backpointers past length)
    for (int t2 = L - 1 + lane; t2 < TT; t2 += 64) out[OFF_VIT + b * TT + t2] = (float)idx;
    if (lane == 0) {
      int cur = idx;
      for (int tt = L - 2; tt >= 0; --tt) {
        cur = bp_s[tt * CC + cur];
        out[OFF_VIT + b * TT + tt] = (float)cur;
      }
      out[OFF_LEN + b] = (float)L;
    }
  } else {
    if (wave == 1) out[OFF_TR + b * 64 + lane] = trans[b * 64 + lane];  // 64 f/block
    const float4* src = (const float4*)pin;
    float4* dst = (float4*)(out + OFF_INP + (size_t)b * TT * CC);
    for (int i = tid - 64; i < TT * CC / 4; i += NTH - 64) dst[i] = src[i];
  }
}

extern "C" void kernel_launch(void* const* d_in, const int* in_sizes, int n_in,
                              void* d_out, int out_size, void* d_ws, size_t ws_size,
                              hipStream_t stream) {
  const float* inputs = (const float*)d_in[0];
  const unsigned char* mask = (const unsigned char*)d_in[1];
  const float* trans = (const float*)d_in[2];
  float* out = (float*)d_out;

  crf_viterbi<<<BB, NTH, SMEM_BYTES, stream>>>(inputs, mask, trans, out);
}